// Round 4
// baseline (326.099 us; speedup 1.0000x reference)
//
#include <hip/hip_runtime.h>
#include <hip/hip_cooperative_groups.h>
#include <math.h>

namespace cg = cooperative_groups;

// ---------------- constants (fp64, folded at compile time) ----------------
#define PI_D      3.14159265358979323846
#define K_D       (1.0 / 44100.0)
#define MAX_OM_D  (10000.0 * 2.0 * PI_D)
#define LN10      2.30258509299404568402
#define ALPHA_D   (3.0 * LN10 / 6.0)                 // DOMSQ == OM2^2 -> 3*ln10/6
#define OM2_D     (2.0 * PI_D * 500.0)
#define BETA_D    (3.0 * LN10 / (OM2_D * OM2_D) * (1.0 / 2.0 - 1.0 / 6.0))
#define LOG2E_D   1.44269504088896340736
#define INV2PI_D  0.15915494309189533577

#define NMODES  6400
#define TPB     256
#define NS      6                 // samples per thread (stride 256)
#define TILE    (TPB * NS)        // 1536 samples per time-tile
#define NCHUNK  32
#define CHUNK_M (NMODES / NCHUNK) // 200 modes per block

#if defined(__has_builtin) && __has_builtin(__builtin_amdgcn_sinf)
#define SIN_REV(x) __builtin_amdgcn_sinf(x)        // v_sin_f32: revolutions
#else
#define SIN_REV(x) __sinf((x) * 6.28318530717958647692f)
#endif
#if defined(__has_builtin) && __has_builtin(__builtin_amdgcn_cosf)
#define COS_REV(x) __builtin_amdgcn_cosf(x)
#else
#define COS_REV(x) __cosf((x) * 6.28318530717958647692f)
#endif
#if defined(__has_builtin) && __has_builtin(__builtin_amdgcn_exp2f)
#define EXP2F(x) __builtin_amdgcn_exp2f(x)
#else
#define EXP2F(x) exp2f(x)
#endif
#if defined(__has_builtin) && __has_builtin(__builtin_amdgcn_fractf)
#define FRACTF(x) __builtin_amdgcn_fractf(x)
#else
#define FRACTF(x) ((x) - floorf(x))
#endif

__device__ inline double softplus_fast(double x) {   // fp32 trans is plenty (rel err 1e-7)
    float xf = (float)x;
    float r = (xf > 0.0f) ? xf + log1pf(__expf(-xf)) : log1pf(__expf(xf));
    return (double)r;
}
__device__ inline float cosrev_d(double x) { return COS_REV((float)(x - floor(x))); }
__device__ inline float sinrev_d(double x) { return SIN_REV((float)(x - floor(x))); }
__device__ inline float sigmoid_f(double x) { return 1.0f / (1.0f + __expf((float)(-x))); }

__global__ __launch_bounds__(TPB) void fused_kernel(
        const float* __restrict__ mu_raw,  const float* __restrict__ Dmu_raw,
        const float* __restrict__ Tmu_raw, const float* __restrict__ Ly_raw,
        const float* __restrict__ xo_raw,  const float* __restrict__ yo_raw,
        float* __restrict__ out, float* __restrict__ disp,
        unsigned int* __restrict__ gmax, int T, int gx) {
    cg::grid_group grid = cg::this_grid();
    const int tid  = threadIdx.x;
    const int bid  = blockIdx.x;
    const int gtid = bid * TPB + tid;
    const int nthr = gridDim.x * TPB;

    // ---------- phase 0: zero accumulator + gmax (ws is 0xAA-poisoned) ----------
    for (int k = gtid; k < T; k += nthr) disp[k] = 0.0f;
    if (gtid == 0) *gmax = 0u;
    __threadfence();
    grid.sync();

    // ---------- phase 1: self-staging (each block computes its 200 modes) ----------
    const int tile  = bid % gx;
    const int chunk = bid / gx;
    const int t0    = tile * TILE;

    __shared__ float4 sA[CHUNK_M];   // {base_rev, cb, c1, c2}
    __shared__ float4 sB[CHUNK_M];   // {ph32, decay2, r256, 0}
    __shared__ int    s_cnt;
    __shared__ float  s_red[TPB / 64];
    if (tid == 0) s_cnt = 0;
    __syncthreads();

    if (tid < CHUNK_M) {
        const int i = chunk * CHUNK_M + tid;
        // scalar parameter transforms (fp64 arithmetic, fp32 transcendentals)
        double mu  = softplus_fast((double)mu_raw[0])  + 1e-4;
        double Dmu = softplus_fast((double)Dmu_raw[0]) + 1e-4;
        double Tmu = softplus_fast((double)Tmu_raw[0]) + 1e-4;
        double Ly  = 1.1 + (4.0 - 1.1) * (((double)tanhf(Ly_raw[0]) + 1.0) * 0.5);
        double xo  = 0.49 + 0.51 * (((double)tanhf(xo_raw[0]) + 1.0) * 0.5);  // LX=1
        double yoL = 0.51 + 0.49 * (((double)tanhf(yo_raw[0]) + 1.0) * 0.5);  // yo/Ly

        int m = i / 80 + 1, n = i % 80 + 1;
        double md = (double)m, nd = (double)n;
        double a  = md * PI_D;
        double b  = nd * PI_D / Ly;
        double g1 = a * a + b * b;
        double omsq  = Tmu * g1 + Dmu * g1 * g1;
        double omega = sqrt(omsq > 0.0 ? omsq : 0.0);

        float valid = sigmoid_f((MAX_OM_D - omega) * 0.01) *
                      sigmoid_f((omega - 40.0 * PI_D) * 0.01);
        float in_w  = cosrev_d(0.1675 * md) * cosrev_d(0.2335 * nd);   // yi/Ly=0.467
        float out_w = cosrev_d(0.5 * xo * md) * cosrev_d(0.5 * yoL * nd);

        double sigma = ALPHA_D + BETA_D * omega * omega;
        double ph64  = omega * K_D * INV2PI_D;         // revolutions per sample
        float envK = __expf((float)(-sigma * K_D));
        float P    = out_w * in_w * (float)(K_D * K_D / (0.25 * mu * Ly)) * envK * valid;
        float coef = P / (sinrev_d(ph64) + 1e-8f);
        float dec2 = (float)(-sigma * K_D * LOG2E_D);  // env = 2^(dec2 * t)

        float cb = coef * EXP2F(dec2 * (float)t0);     // coef * env(t0); 0 if dead/gated
        if (cb != 0.0f) {
            double bd  = ph64 * (double)(t0 + 1);      // sine-arg revs at local i=0 base
            float base = (float)(bd - floor(bd));
            float r256 = EXP2F(dec2 * 256.0f);         // rho^256
            float c1   = 2.0f * r256 * cosrev_d(ph64 * 256.0);
            float c2   = r256 * r256;
            int idx = atomicAdd(&s_cnt, 1);
            sA[idx] = make_float4(base, cb, c1, c2);
            sB[idx] = make_float4((float)ph64, dec2, r256, 0.0f);
        }
    }
    __syncthreads();
    const int n_act = s_cnt;

    // ---------- phase 2: synth — seed 2 samples, recur 4 (stride-256 recurrence) ----------
    float acc[NS];
    #pragma unroll
    for (int i = 0; i < NS; ++i) acc[i] = 0.0f;
    const float tidf = (float)tid;

    for (int j = 0; j < n_act; ++j) {
        float4 a = sA[j];                       // broadcast ds_read_b128
        float4 b = sB[j];
        float ang0 = fmaf(b.x, tidf, a.x);      // revs at i=0 (|.| < 120 -> fp32 ok)
        float ang1 = fmaf(b.x, 256.0f, ang0);   // revs at i=1
        float s0 = SIN_REV(FRACTF(ang0));
        float s1 = SIN_REV(FRACTF(ang1));
        float ce = a.y * EXP2F(b.y * tidf);     // coef * env(t0 + tid)
        float y0 = ce * s0;
        float y1 = ce * b.z * s1;               // * rho^256
        acc[0] += y0;
        acc[1] += y1;
        #pragma unroll
        for (int i = 2; i < NS; ++i) {
            float y2 = fmaf(a.z, y1, -(a.w * y0));   // c1*y1 - c2*y0
            acc[i] += y2;
            y0 = y1; y1 = y2;
        }
    }
    #pragma unroll
    for (int i = 0; i < NS; ++i) {
        int t = t0 + tid + 256 * i;
        if (t < T) atomicAdd(&disp[t], acc[i]);
    }
    __threadfence();
    grid.sync();

    // ---------- phase 3: diff + global abs-max (parallel) ----------
    float lmax = 0.0f;
    for (int t = gtid; t < T; t += nthr) {
        float p = (t > 0) ? disp[t - 1] : 0.0f;
        float v = (disp[t] - p) * 44100.0f;     // ir = diff / K
        out[t] = v;
        lmax = fmaxf(lmax, fabsf(v));
    }
    for (int o = 32; o > 0; o >>= 1)
        lmax = fmaxf(lmax, __shfl_down(lmax, o, 64));
    if ((tid & 63) == 0) s_red[tid >> 6] = lmax;
    __syncthreads();
    if (tid == 0) {
        float m0 = fmaxf(fmaxf(s_red[0], s_red[1]), fmaxf(s_red[2], s_red[3]));
        atomicMax(gmax, __float_as_uint(m0));   // valid: values >= 0
    }
    __threadfence();
    grid.sync();

    // ---------- phase 4: normalize ----------
    const float inv = 1.0f / (__uint_as_float(*gmax) + 1e-8f);
    for (int t = gtid; t < T; t += nthr)
        out[t] *= inv;
}

extern "C" void kernel_launch(void* const* d_in, const int* in_sizes, int n_in,
                              void* d_out, int out_size, void* d_ws, size_t ws_size,
                              hipStream_t stream) {
    const float* mu_raw  = (const float*)d_in[0];
    const float* Dmu_raw = (const float*)d_in[1];
    const float* Tmu_raw = (const float*)d_in[2];
    const float* Ly_raw  = (const float*)d_in[3];
    const float* xo_raw  = (const float*)d_in[4];
    const float* yo_raw  = (const float*)d_in[5];
    float* out = (float*)d_out;
    int T = out_size;
    if (T <= 0) return;

    char* ws = (char*)d_ws;
    float* disp = (float*)(ws + 0);                       // T*4 B
    unsigned int* gmax = (unsigned int*)(ws + (((size_t)T * 4 + 255) & ~255ULL));

    int gx = (T + TILE - 1) / TILE;                       // time tiles (15 for T=22050)
    dim3 grid(gx * NCHUNK), block(TPB);                   // 480 blocks — co-resident

    void* args[] = { (void*)&mu_raw, (void*)&Dmu_raw, (void*)&Tmu_raw,
                     (void*)&Ly_raw, (void*)&xo_raw, (void*)&yo_raw,
                     (void*)&out, (void*)&disp, (void*)&gmax,
                     (void*)&T, (void*)&gx };
    hipLaunchCooperativeKernel((void*)fused_kernel, grid, block, args, 0, stream);
}

// Round 5
// 96.523 us; speedup vs baseline: 3.3784x; 3.3784x over previous
//
#include <hip/hip_runtime.h>
#include <math.h>

// ---------------- constants (fp64, folded at compile time) ----------------
#define PI_D      3.14159265358979323846
#define K_D       (1.0 / 44100.0)
#define MAX_OM_D  (10000.0 * 2.0 * PI_D)
#define LN10      2.30258509299404568402
#define ALPHA_D   (3.0 * LN10 / 6.0)                 // DOMSQ == OM2^2 -> 3*ln10/6
#define OM2_D     (2.0 * PI_D * 500.0)
#define BETA_D    (3.0 * LN10 / (OM2_D * OM2_D) * (1.0 / 2.0 - 1.0 / 6.0))
#define LOG2E_D   1.44269504088896340736
#define INV2PI_D  0.15915494309189533577

#define NMODES  6400
#define TPB     256
#define NS      6                 // samples per thread (stride TPB)
#define TILE    (TPB * NS)        // 1536 samples per time-tile
#define NCHUNK  32
#define CHUNK_M (NMODES / NCHUNK) // 200 modes per block

#if defined(__has_builtin) && __has_builtin(__builtin_amdgcn_sinf)
#define SIN_REV(x) __builtin_amdgcn_sinf(x)        // v_sin_f32: revolutions
#else
#define SIN_REV(x) __sinf((x) * 6.28318530717958647692f)
#endif
#if defined(__has_builtin) && __has_builtin(__builtin_amdgcn_cosf)
#define COS_REV(x) __builtin_amdgcn_cosf(x)
#else
#define COS_REV(x) __cosf((x) * 6.28318530717958647692f)
#endif
#if defined(__has_builtin) && __has_builtin(__builtin_amdgcn_exp2f)
#define EXP2F(x) __builtin_amdgcn_exp2f(x)
#else
#define EXP2F(x) exp2f(x)
#endif
#if defined(__has_builtin) && __has_builtin(__builtin_amdgcn_fractf)
#define FRACTF(x) __builtin_amdgcn_fractf(x)
#else
#define FRACTF(x) ((x) - floorf(x))
#endif

__device__ inline double softplus_fast(double x) {
    float xf = (float)x;
    float r = (xf > 0.0f) ? xf + log1pf(__expf(-xf)) : log1pf(__expf(xf));
    return (double)r;
}
__device__ inline float cosrev_d(double x) { return COS_REV((float)(x - floor(x))); }
__device__ inline float sinrev_d(double x) { return SIN_REV((float)(x - floor(x))); }
__device__ inline float sigmoid_f(double x) { return 1.0f / (1.0f + __expf((float)(-x))); }

// ------- kernel 1: per-mode params (incl. recurrence consts) + zero disp/gmax -------
__global__ void mode_params_kernel(const float* __restrict__ mu_raw,
                                   const float* __restrict__ Dmu_raw,
                                   const float* __restrict__ Tmu_raw,
                                   const float* __restrict__ Ly_raw,
                                   const float* __restrict__ xo_raw,
                                   const float* __restrict__ yo_raw,
                                   double* __restrict__ phase64,  // revs/sample
                                   float4* __restrict__ pdA,      // {coef, dec2, c1, c2}
                                   float4* __restrict__ pdB,      // {ph32, d256, r256, 0}
                                   float* __restrict__ disp,
                                   unsigned int* __restrict__ gmax, int T) {
    int i = blockIdx.x * blockDim.x + threadIdx.x;

    // zero accumulator + gmax (ws is 0xAA-poisoned before every call)
    for (int k = i; k < T; k += gridDim.x * blockDim.x) disp[k] = 0.0f;
    if (i == 0) *gmax = 0u;

    if (i >= NMODES) return;

    double mu  = softplus_fast((double)mu_raw[0])  + 1e-4;
    double Dmu = softplus_fast((double)Dmu_raw[0]) + 1e-4;
    double Tmu = softplus_fast((double)Tmu_raw[0]) + 1e-4;
    double Ly  = 1.1 + (4.0 - 1.1) * (((double)tanhf(Ly_raw[0]) + 1.0) * 0.5);
    double xo  = 0.49 + 0.51 * (((double)tanhf(xo_raw[0]) + 1.0) * 0.5);  // LX=1
    double yoL = 0.51 + 0.49 * (((double)tanhf(yo_raw[0]) + 1.0) * 0.5);  // yo/Ly

    int m = i / 80 + 1, n = i % 80 + 1;
    double md = (double)m, nd = (double)n;
    double invLy = 1.0 / Ly;
    double a  = md * PI_D;
    double b  = nd * PI_D * invLy;
    double g1 = a * a + b * b;
    double omsq  = Tmu * g1 + Dmu * g1 * g1;
    double omega = sqrt(omsq > 0.0 ? omsq : 0.0);

    float valid = sigmoid_f((MAX_OM_D - omega) * 0.01) *
                  sigmoid_f((omega - 40.0 * PI_D) * 0.01);
    float in_w  = cosrev_d(0.1675 * md) * cosrev_d(0.2335 * nd);   // yi/Ly = 0.467
    float out_w = cosrev_d(0.5 * xo * md) * cosrev_d(0.5 * yoL * nd);

    double sigma = ALPHA_D + BETA_D * omega * omega;
    double ph64  = omega * K_D * INV2PI_D;          // revolutions per sample
    float envK = __expf((float)(-sigma * K_D));
    float P    = out_w * in_w * (float)(K_D * K_D / (0.25 * mu * Ly)) * envK * valid;
    float coef = P / (sinrev_d(ph64) + 1e-8f);
    float dec2 = (float)(-sigma * K_D * LOG2E_D);   // env = 2^(dec2*t)

    // block-invariant stride-256 recurrence constants (fp64 phase reduction)
    float r256 = EXP2F(dec2 * 256.0f);              // rho^256
    double p256 = ph64 * 256.0;
    float d256 = (float)(p256 - floor(p256));       // fract of 256-sample phase step
    float c1 = 2.0f * r256 * COS_REV(d256);
    float c2 = r256 * r256;

    phase64[i] = ph64;
    pdA[i] = make_float4(coef, dec2, c1, c2);
    pdB[i] = make_float4((float)ph64, d256, r256, 0.0f);
}

// ------- kernel 2: synth — seed 2 samples, recur NS-2 (stride-256 recurrence) -------
__global__ __launch_bounds__(TPB) void synth_kernel(const double* __restrict__ phase64,
                                                    const float4* __restrict__ pdA,
                                                    const float4* __restrict__ pdB,
                                                    float* __restrict__ disp, int T) {
    __shared__ float4 sA[CHUNK_M];   // {base, cb, c1, c2}
    __shared__ float4 sB[CHUNK_M];   // {ph32, d256, r256, dec2}
    __shared__ int    s_cnt;

    const int m0 = blockIdx.y * CHUNK_M;
    const int t0 = blockIdx.x * TILE;
    const int tid = threadIdx.x;

    if (tid == 0) s_cnt = 0;
    __syncthreads();

    // staging: compute cb + fp64 phase base, compact live modes into LDS
    if (tid < CHUNK_M) {
        float4 p = pdA[m0 + tid];
        float cb = p.x * EXP2F(p.y * (float)t0);    // coef * env(t0); 0 when dead/gated
        if (cb != 0.0f) {
            float4 q = pdB[m0 + tid];
            double bd = phase64[m0 + tid] * (double)(t0 + 1);   // revs at local i=0, tid=0
            float base = (float)(bd - floor(bd));
            int idx = atomicAdd(&s_cnt, 1);
            sA[idx] = make_float4(base, cb, p.z, p.w);
            sB[idx] = make_float4(q.x, q.y, q.z, p.y);
        }
    }
    __syncthreads();
    const int n_act = s_cnt;

    float acc[NS];
    #pragma unroll
    for (int i = 0; i < NS; ++i) acc[i] = 0.0f;
    const float tidf = (float)tid;

    for (int j = 0; j < n_act; ++j) {
        float4 a = sA[j];                       // broadcast ds_read_b128 x2
        float4 b = sB[j];
        float ang0 = fmaf(b.x, tidf, a.x);      // revs, |.| < 60 -> fp32 ok
        float s0 = SIN_REV(FRACTF(ang0));
        float s1 = SIN_REV(FRACTF(ang0 + b.y)); // + fp64-reduced 256-step
        float ce = a.y * EXP2F(b.w * tidf);     // coef*env(t0+tid)
        float y0 = ce * s0;
        float y1 = ce * b.z * s1;               // * rho^256
        acc[0] += y0;
        acc[1] += y1;
        #pragma unroll
        for (int i = 2; i < NS; ++i) {
            float y2 = fmaf(a.z, y1, -(a.w * y0));   // c1*y1 - c2*y0
            acc[i] += y2;
            y0 = y1; y1 = y2;
        }
    }
    #pragma unroll
    for (int i = 0; i < NS; ++i) {
        int t = t0 + tid + TPB * i;
        if (t < T) atomicAdd(&disp[t], acc[i]);
    }
}

// ------- kernel 3: diff + per-block abs-max + global atomicMax -------
__global__ void diff_max_kernel(const float* __restrict__ disp,
                                float* __restrict__ out,
                                unsigned int* __restrict__ gmax, int T) {
    __shared__ float s_red[TPB / 64];
    int t = blockIdx.x * blockDim.x + threadIdx.x;
    float v = 0.0f;
    if (t < T) {
        float p = (t > 0) ? disp[t - 1] : 0.0f;
        v = (disp[t] - p) * 44100.0f;           // ir = diff / K
        out[t] = v;
    }
    float lmax = fabsf(v);
    for (int o = 32; o > 0; o >>= 1)
        lmax = fmaxf(lmax, __shfl_down(lmax, o, 64));
    if ((threadIdx.x & 63) == 0) s_red[threadIdx.x >> 6] = lmax;
    __syncthreads();
    if (threadIdx.x == 0) {
        float m0 = fmaxf(fmaxf(s_red[0], s_red[1]), fmaxf(s_red[2], s_red[3]));
        atomicMax(gmax, __float_as_uint(m0));   // valid: non-negative floats
    }
}

// ------- kernel 4: normalize -------
__global__ void normalize_kernel(float* __restrict__ out,
                                 const unsigned int* __restrict__ gmax, int T) {
    int t = blockIdx.x * blockDim.x + threadIdx.x;
    if (t >= T) return;
    out[t] = out[t] / (__uint_as_float(*gmax) + 1e-8f);
}

extern "C" void kernel_launch(void* const* d_in, const int* in_sizes, int n_in,
                              void* d_out, int out_size, void* d_ws, size_t ws_size,
                              hipStream_t stream) {
    const float* mu_raw  = (const float*)d_in[0];
    const float* Dmu_raw = (const float*)d_in[1];
    const float* Tmu_raw = (const float*)d_in[2];
    const float* Ly_raw  = (const float*)d_in[3];
    const float* xo_raw  = (const float*)d_in[4];
    const float* yo_raw  = (const float*)d_in[5];
    float* out = (float*)d_out;
    int T = out_size;
    if (T <= 0) return;

    // workspace layout
    char* ws = (char*)d_ws;
    double* phase64 = (double*)(ws + 0);              //  51200 B
    float4* pdA     = (float4*)(ws + 51200);          // 102400 B
    float4* pdB     = (float4*)(ws + 153600);         // 102400 B
    unsigned int* gmax = (unsigned int*)(ws + 256000);
    float*  disp    = (float*)(ws + 256256);          // T*4 B

    int nb = ((T > NMODES ? T : NMODES) + TPB - 1) / TPB;
    mode_params_kernel<<<nb, TPB, 0, stream>>>(
        mu_raw, Dmu_raw, Tmu_raw, Ly_raw, xo_raw, yo_raw,
        phase64, pdA, pdB, disp, gmax, T);

    dim3 grid((T + TILE - 1) / TILE, NCHUNK);
    synth_kernel<<<grid, TPB, 0, stream>>>(phase64, pdA, pdB, disp, T);

    int nb2 = (T + TPB - 1) / TPB;
    diff_max_kernel<<<nb2, TPB, 0, stream>>>(disp, out, gmax, T);
    normalize_kernel<<<nb2, TPB, 0, stream>>>(out, gmax, T);
}